// Round 11
// baseline (236.486 us; speedup 1.0000x reference)
//
#include <hip/hip_runtime.h>

#define C_IN  128
#define C_HID 128
#define C_OUT 64

typedef __attribute__((ext_vector_type(8))) short short8;
typedef __attribute__((ext_vector_type(4))) float f32x4;

// bf16 helpers (RNE)
__device__ __forceinline__ unsigned f2bf(float f) {
    unsigned u = __float_as_uint(f);
    return (u + 0x7FFF + ((u >> 16) & 1)) >> 16;
}
__device__ __forceinline__ float bflo(unsigned t) { return __uint_as_float(t << 16); }
__device__ __forceinline__ float bfhi(unsigned t) { return __uint_as_float(t & 0xFFFF0000u); }

// ================= x f32 -> bf16 (packed) =================

__global__ __launch_bounds__(256) void k_cvt(const float4* __restrict__ in, uint2* __restrict__ outp, int n4) {
    int i = blockIdx.x * 256 + threadIdx.x;
    if (i < n4) {
        float4 v = in[i];
        uint2 o;
        o.x = (f2bf(v.y) << 16) | f2bf(v.x);
        o.y = (f2bf(v.w) << 16) | f2bf(v.z);
        outp[i] = o;
    }
}

// ================= CSR build =================

__global__ __launch_bounds__(256) void k_count(const int* __restrict__ ei, int* __restrict__ cnt, int E) {
    int e = blockIdx.x * 256 + threadIdx.x;
    if (e < E) atomicAdd(&cnt[ei[E + e]], 1);  // dst
}

__global__ __launch_bounds__(256) void k_dinv(const int* __restrict__ cnt, float* __restrict__ dinv, int n) {
    int i = blockIdx.x * 256 + threadIdx.x;
    if (i < n) dinv[i] = rsqrtf((float)(cnt[i] + 1));  // +1 self-loop
}

__global__ __launch_bounds__(256) void k_scan1(const int* __restrict__ cnt, int* __restrict__ row_ptr,
                                               int* __restrict__ bsum, int n) {
    __shared__ int s[256];
    int tid = threadIdx.x;
    int i = blockIdx.x * 256 + tid;
    int v = (i < n) ? cnt[i] : 0;
    s[tid] = v;
    __syncthreads();
    #pragma unroll
    for (int off = 1; off < 256; off <<= 1) {
        int t = (tid >= off) ? s[tid - off] : 0;
        __syncthreads();
        s[tid] += t;
        __syncthreads();
    }
    if (i < n) row_ptr[i] = s[tid] - v;
    if (tid == 255) bsum[blockIdx.x] = s[255];
}

__global__ __launch_bounds__(256) void k_scan2(const int* __restrict__ bsum, int* __restrict__ bpre, int nb) {
    __shared__ int s[256];
    int tid = threadIdx.x;
    int v = (tid < nb) ? bsum[tid] : 0;
    s[tid] = v;
    __syncthreads();
    #pragma unroll
    for (int off = 1; off < 256; off <<= 1) {
        int t = (tid >= off) ? s[tid - off] : 0;
        __syncthreads();
        s[tid] += t;
        __syncthreads();
    }
    if (tid < nb) bpre[tid] = s[tid] - v;
}

__global__ __launch_bounds__(256) void k_scan3(int* __restrict__ row_ptr, int* __restrict__ cursor,
                                               const int* __restrict__ bpre, int n, int E) {
    int i = blockIdx.x * 256 + threadIdx.x;
    if (i < n) {
        int r = row_ptr[i] + bpre[blockIdx.x];
        row_ptr[i] = r;
        cursor[i] = r;
    }
    if (i == 0) row_ptr[n] = E;
}

// ---- two-level bucket fill: bucket = 16 consecutive dsts; CSR region of a bucket is
// contiguous [row_ptr[16b], row_ptr[16b+16]), so bucket cursors come straight from row_ptr.

__global__ __launch_bounds__(256) void k_bcur(const int* __restrict__ row_ptr, int* __restrict__ bcur,
                                              int n, int nbk) {
    int b = blockIdx.x * 256 + threadIdx.x;
    if (b < nbk) bcur[b] = row_ptr[min(b * 16, n)];
}

// Pass A: scatter packed (src<<4 | dst&15) into the dst's bucket region.
// Bucket tail-lines are few (200KB) -> L2-resident -> ~16 entries/line vs 1 for random.
__global__ __launch_bounds__(256) void k_fillA(const int* __restrict__ ei, int* __restrict__ bcur,
                                               unsigned* __restrict__ tmp, int E) {
    int e = blockIdx.x * 256 + threadIdx.x;
    if (e >= E) return;
    int s = ei[e];
    int d = ei[E + e];
    int pos = atomicAdd(&bcur[d >> 4], 1);
    tmp[pos] = ((unsigned)s << 4) | (unsigned)(d & 15);
}

// Pass B: one block per bucket; coalesced region read, LDS per-dst cursors, writes stay
// inside the same small region (single block -> dense line fill, no global atomics).
__global__ __launch_bounds__(256) void k_fillB(const unsigned* __restrict__ tmp,
                                               const int* __restrict__ row_ptr,
                                               int* __restrict__ csr_src, int n) {
    __shared__ int cur[16];
    const int base = blockIdx.x * 16;
    if (threadIdx.x < 16) cur[threadIdx.x] = row_ptr[min(base + (int)threadIdx.x, n)];
    __syncthreads();
    const int start = row_ptr[min(base, n)];
    const int end   = row_ptr[min(base + 16, n)];
    for (int i = start + (int)threadIdx.x; i < end; i += 256) {
        unsigned u = tmp[i];
        int pos = atomicAdd(&cur[u & 15], 1);   // LDS atomic
        csr_src[pos] = (int)(u >> 4);
    }
}

// ================= MFMA GEMM: H'bf16[M,N] = dinv[row] * (Xbf16[M,128] @ Wf32[128,N]) =================
// 256 thr = 4 waves; wave w owns 16-row strip (M % 16 == 0). mfma_f32_16x16x32_bf16.
// Output rows pre-scaled by dinv[row] -> aggregation needs NO per-edge coefficients:
//   agg[v] = dinv[v] * (h'[v] + sum_{s in N(v)} h'[s]) + bias.

template<int N>
__global__ __launch_bounds__(256) void k_gemm_mfma(const unsigned short* __restrict__ X,
                                                   const float* __restrict__ W,
                                                   const float* __restrict__ dinv,
                                                   unsigned short* __restrict__ H, int M) {
    constexpr int K = 128;
    constexpr int LDT = K + 8;                 // pad: 2-way-free b128 reads
    __shared__ unsigned short sWt[N * LDT];

    const int tid = threadIdx.x;
    // stage W transposed as bf16 (coalesced f32 reads)
    constexpr int NLOG = (N == 128) ? 7 : 6;
    for (int idx = tid; idx < K * N; idx += 256) {
        int k = idx >> NLOG, c = idx & (N - 1);
        sWt[c * LDT + k] = (unsigned short)f2bf(W[idx]);
    }
    __syncthreads();

    const int wave = __builtin_amdgcn_readfirstlane(tid >> 6);
    const int lane = tid & 63;
    const int m0 = blockIdx.x * 64 + wave * 16;
    if (m0 >= M) return;                        // no syncthreads after this point

    const int arow = lane & 15;
    const int koff = (lane >> 4) * 8;

    // A fragments: 16B each, k0 = 0,32,64,96
    const unsigned short* ap = X + (size_t)(m0 + arow) * K + koff;
    short8 a[4];
    #pragma unroll
    for (int q = 0; q < 4; ++q) a[q] = *(const short8*)(ap + q * 32);

    const int row0 = m0 + (lane >> 4) * 4;
    const float4 dv = *(const float4*)(dinv + row0);   // row0 % 4 == 0, dinv 16B-aligned

    #pragma unroll
    for (int ct = 0; ct < N / 16; ++ct) {
        const int bcol = ct * 16 + (lane & 15);
        const unsigned short* bp = &sWt[bcol * LDT + koff];
        f32x4 acc = {0.f, 0.f, 0.f, 0.f};
        #pragma unroll
        for (int q = 0; q < 4; ++q) {
            short8 b = *(const short8*)(bp + q * 32);
            acc = __builtin_amdgcn_mfma_f32_16x16x32_bf16(a[q], b, acc, 0, 0, 0);
        }
        const int col = ct * 16 + (lane & 15);
        #pragma unroll
        for (int r = 0; r < 4; ++r) {
            float dr = (r == 0) ? dv.x : (r == 1) ? dv.y : (r == 2) ? dv.z : dv.w;
            H[(size_t)(row0 + r) * N + col] = (unsigned short)f2bf(acc[r] * dr);
        }
    }
}

// ================= aggregation over pre-scaled bf16 h': wave owns G=4 nodes, U=16 batches =================
// acc[g] = h'[v] + sum h'[s]  (unweighted!) ; out = dinv[v]*acc + bias (f32 epilogue).
// C=128: lane owns cols (2l,2l+1): one uint gather/lane. C=64: lane owns col l: ushort gather.
// OUTBF: store packed bf16 (feeds next MFMA GEMM); else f32.

template<int C, bool RELU, bool OUTBF>
__global__ __launch_bounds__(256) void k_agg(const void* __restrict__ hraw,
                                             const int* __restrict__ row_ptr,
                                             const int* __restrict__ csr_src,
                                             const float* __restrict__ dinv,
                                             const float* __restrict__ bias,
                                             void* __restrict__ agg, int n) {
    constexpr int G = 4;
    constexpr int U = 16;
    constexpr int VPC = C / 64;          // 2 (C=128) or 1 (C=64)
    const int lane = threadIdx.x & 63;
    const int wv = __builtin_amdgcn_readfirstlane(threadIdx.x >> 6);
    const int v0 = (blockIdx.x * 4 + wv) * G;
    if (v0 >= n) return;

    const unsigned*       hu = (const unsigned*)hraw;        // C=128 view
    const unsigned short* hs = (const unsigned short*)hraw;  // C=64 view

    int rp[G + 1];
    #pragma unroll
    for (int g = 0; g <= G; ++g) rp[g] = row_ptr[min(v0 + g, n)];

    float dd[G];
    float acc[G][VPC];
    #pragma unroll
    for (int g = 0; g < G; ++g) {
        #pragma unroll
        for (int u = 0; u < VPC; ++u) acc[g][u] = 0.f;
        dd[g] = 0.f;
        if (v0 + g < n) {
            dd[g] = dinv[v0 + g];
            if (VPC == 2) {
                unsigned t = hu[(size_t)(v0 + g) * 64 + lane];
                acc[g][0] = bflo(t);
                acc[g][1] = bfhi(t);
            } else {
                acc[g][0] = bflo(hs[(size_t)(v0 + g) * 64 + lane]);
            }
        }
    }

    const int e = rp[G];
    for (int j0 = rp[0]; j0 < e; j0 += U) {
        int ss[U];
        #pragma unroll
        for (int u = 0; u < U; ++u) {
            int s = csr_src[j0 + u];          // contiguous scalar loads
                                              // (<=60B overread into next ws buffer)
            ss[u] = (j0 + u < e) ? s : 0;     // clamp OOB slots
        }
        float hv[U][VPC];
        #pragma unroll
        for (int u = 0; u < U; ++u) {
            if (VPC == 2) {
                unsigned t = hu[(size_t)ss[u] * 64 + lane];
                hv[u][0] = bflo(t);
                hv[u][1] = bfhi(t);
            } else {
                hv[u][0] = bflo(hs[(size_t)ss[u] * 64 + lane]);
            }
        }
        #pragma unroll
        for (int u = 0; u < U; ++u) {
            const int jj = j0 + u;
            #pragma unroll
            for (int g = 0; g < G; ++g) {
                bool in_g = (jj >= rp[g]) && (jj < rp[g + 1]);  // wave-uniform; OOB -> none
                float cg = in_g ? 1.f : 0.f;
                #pragma unroll
                for (int u2 = 0; u2 < VPC; ++u2) acc[g][u2] += cg * hv[u][u2];
            }
        }
    }

    #pragma unroll
    for (int g = 0; g < G; ++g) {
        if (v0 + g < n) {
            if (VPC == 2) {
                float2 bv = ((const float2*)bias)[lane];   // bias[2l], bias[2l+1]
                float ox = acc[g][0] * dd[g] + bv.x;
                float oy = acc[g][1] * dd[g] + bv.y;
                if (RELU) { ox = fmaxf(ox, 0.f); oy = fmaxf(oy, 0.f); }
                if (OUTBF) {
                    ((unsigned*)agg)[(size_t)(v0 + g) * 64 + lane] = (f2bf(oy) << 16) | f2bf(ox);
                } else {
                    ((float2*)agg)[(size_t)(v0 + g) * 64 + lane] = make_float2(ox, oy);
                }
            } else {
                float o = acc[g][0] * dd[g] + bias[lane];
                if (RELU) o = fmaxf(o, 0.f);
                if (OUTBF) ((unsigned short*)agg)[(size_t)(v0 + g) * 64 + lane] = (unsigned short)f2bf(o);
                else       ((float*)agg)[(size_t)(v0 + g) * 64 + lane] = o;
            }
        }
    }
}

// ================= launch =================

extern "C" void kernel_launch(void* const* d_in, const int* in_sizes, int n_in,
                              void* d_out, int out_size, void* d_ws, size_t ws_size,
                              hipStream_t stream) {
    const float* x  = (const float*)d_in[0];
    const int*   ei = (const int*)d_in[1];
    const float* W1 = (const float*)d_in[2];
    const float* b1 = (const float*)d_in[3];
    const float* W2 = (const float*)d_in[4];
    const float* b2 = (const float*)d_in[5];
    float* out = (float*)d_out;

    const int N = in_sizes[0] / C_IN;   // 50000
    const int E = in_sizes[1] / 2;      // 800000
    const int NBK = (N + 15) / 16;      // 3125 buckets of 16 dsts

    // 16B-aligned workspace layout
    char* base = (char*)d_ws;
    size_t off = 0;
    auto alloc = [&](size_t bytes) {
        char* q = base + off;
        off = (off + bytes + 15) & ~(size_t)15;
        return q;
    };
    int*   cnt      = (int*)  alloc((size_t)N * 4);
    float* dinv     = (float*)alloc((size_t)N * 4);
    int*   row_ptr  = (int*)  alloc((size_t)(N + 1) * 4);
    int*   cursor   = (int*)  alloc((size_t)N * 4);
    int*   bsum     = (int*)  alloc(256 * 4);
    int*   bpre     = (int*)  alloc(256 * 4);
    int*   bcur     = (int*)  alloc((size_t)NBK * 4);
    unsigned* tmp   = (unsigned*)alloc((size_t)E * 4);
    int*   csr_src  = (int*)  alloc((size_t)E * 4);
    unsigned short* xb   = (unsigned short*)alloc((size_t)N * C_IN * 2);   // bf16 x
    unsigned short* h    = (unsigned short*)alloc((size_t)N * C_HID * 2);  // bf16 h' / h2'
    unsigned short* agg1 = (unsigned short*)alloc((size_t)N * C_HID * 2);  // bf16 agg1
    unsigned short* h2   = h;  // layer-2 h' reuses h (dead after agg128)

    dim3 blk(256);
    const int nbS = (N + 255) / 256;

    k_cvt  <<<((N * C_IN / 4) + 255) / 256, blk, 0, stream>>>((const float4*)x, (uint2*)xb, N * C_IN / 4);

    hipMemsetAsync(cnt, 0, (size_t)N * 4, stream);
    k_count<<<(E + 255) / 256, blk, 0, stream>>>(ei, cnt, E);
    k_dinv <<<nbS, blk, 0, stream>>>(cnt, dinv, N);
    k_scan1<<<nbS, blk, 0, stream>>>(cnt, row_ptr, bsum, N);
    k_scan2<<<1, blk, 0, stream>>>(bsum, bpre, nbS);
    k_scan3<<<nbS, blk, 0, stream>>>(row_ptr, cursor, bpre, N, E);
    k_bcur <<<(NBK + 255) / 256, blk, 0, stream>>>(row_ptr, bcur, N, NBK);
    k_fillA<<<(E + 255) / 256, blk, 0, stream>>>(ei, bcur, tmp, E);
    k_fillB<<<NBK, blk, 0, stream>>>(tmp, row_ptr, csr_src, N);

    const int gblocks = (N + 63) / 64;
    const int ablocks = (N + 15) / 16;   // 4 waves x G=4 nodes per block

    // layer 1: h' = dinv * bf16(xb @ W1) ; agg1 = bf16(relu(dinv*(sum h') + b1))
    k_gemm_mfma<C_HID><<<gblocks, blk, 0, stream>>>(xb, W1, dinv, h, N);
    k_agg<C_HID, true, true><<<ablocks, blk, 0, stream>>>(h, row_ptr, csr_src, dinv, b1, agg1, N);

    // layer 2: h2' = dinv * bf16(agg1 @ W2) ; out = dinv*(sum h2') + b2
    k_gemm_mfma<C_OUT><<<gblocks, blk, 0, stream>>>(agg1, W2, dinv, h2, N);
    k_agg<C_OUT, false, false><<<ablocks, blk, 0, stream>>>(h2, row_ptr, csr_src, dinv, b2, out, N);
}

// Round 12
// 171.418 us; speedup vs baseline: 1.3796x; 1.3796x over previous
//
#include <hip/hip_runtime.h>

#define C_IN  128
#define C_HID 128
#define C_OUT 64

typedef __attribute__((ext_vector_type(8))) short short8;
typedef __attribute__((ext_vector_type(4))) float f32x4;

// bf16 helpers (RNE)
__device__ __forceinline__ unsigned f2bf(float f) {
    unsigned u = __float_as_uint(f);
    return (u + 0x7FFF + ((u >> 16) & 1)) >> 16;
}
__device__ __forceinline__ float bflo(unsigned t) { return __uint_as_float(t << 16); }
__device__ __forceinline__ float bfhi(unsigned t) { return __uint_as_float(t & 0xFFFF0000u); }

// ================= x f32 -> bf16 (packed) =================

__global__ __launch_bounds__(256) void k_cvt(const float4* __restrict__ in, uint2* __restrict__ outp, int n4) {
    int i = blockIdx.x * 256 + threadIdx.x;
    if (i < n4) {
        float4 v = in[i];
        uint2 o;
        o.x = (f2bf(v.y) << 16) | f2bf(v.x);
        o.y = (f2bf(v.w) << 16) | f2bf(v.z);
        outp[i] = o;
    }
}

// ================= CSR build =================
// Single atomic pass: count in-degree AND record each edge's slot within its row
// (pos[e] written coalesced by e). Fill pass then needs no atomics.

__global__ __launch_bounds__(256) void k_count_pos(const int* __restrict__ ei, int* __restrict__ cnt,
                                                   int* __restrict__ pos, int E) {
    int e = blockIdx.x * 256 + threadIdx.x;
    if (e < E) pos[e] = atomicAdd(&cnt[ei[E + e]], 1);  // dst
}

__global__ __launch_bounds__(256) void k_dinv(const int* __restrict__ cnt, float* __restrict__ dinv, int n) {
    int i = blockIdx.x * 256 + threadIdx.x;
    if (i < n) dinv[i] = rsqrtf((float)(cnt[i] + 1));  // +1 self-loop
}

__global__ __launch_bounds__(256) void k_scan1(const int* __restrict__ cnt, int* __restrict__ row_ptr,
                                               int* __restrict__ bsum, int n) {
    __shared__ int s[256];
    int tid = threadIdx.x;
    int i = blockIdx.x * 256 + tid;
    int v = (i < n) ? cnt[i] : 0;
    s[tid] = v;
    __syncthreads();
    #pragma unroll
    for (int off = 1; off < 256; off <<= 1) {
        int t = (tid >= off) ? s[tid - off] : 0;
        __syncthreads();
        s[tid] += t;
        __syncthreads();
    }
    if (i < n) row_ptr[i] = s[tid] - v;
    if (tid == 255) bsum[blockIdx.x] = s[255];
}

__global__ __launch_bounds__(256) void k_scan2(const int* __restrict__ bsum, int* __restrict__ bpre, int nb) {
    __shared__ int s[256];
    int tid = threadIdx.x;
    int v = (tid < nb) ? bsum[tid] : 0;
    s[tid] = v;
    __syncthreads();
    #pragma unroll
    for (int off = 1; off < 256; off <<= 1) {
        int t = (tid >= off) ? s[tid - off] : 0;
        __syncthreads();
        s[tid] += t;
        __syncthreads();
    }
    if (tid < nb) bpre[tid] = s[tid] - v;
}

__global__ __launch_bounds__(256) void k_scan3(int* __restrict__ row_ptr,
                                               const int* __restrict__ bpre, int n, int E) {
    int i = blockIdx.x * 256 + threadIdx.x;
    if (i < n) row_ptr[i] += bpre[blockIdx.x];
    if (i == 0) row_ptr[n] = E;
}

// atomic-free fill: slot = row_ptr[d] + pos[e] is unique per edge.
__global__ __launch_bounds__(256) void k_fill2(const int* __restrict__ ei,
                                               const int* __restrict__ row_ptr,
                                               const int* __restrict__ pos,
                                               int* __restrict__ csr_src, int E) {
    int e = blockIdx.x * 256 + threadIdx.x;
    if (e >= E) return;
    int s = ei[e];
    int d = ei[E + e];
    csr_src[row_ptr[d] + pos[e]] = s;
}

// ================= MFMA GEMM: H'bf16[M,N] = dinv[row] * (Xbf16[M,128] @ Wf32[128,N]) =================
// 256 thr = 4 waves; wave w owns 16-row strip (M % 16 == 0). mfma_f32_16x16x32_bf16.
// Output rows pre-scaled by dinv[row] -> aggregation needs NO per-edge coefficients:
//   agg[v] = dinv[v] * (h'[v] + sum_{s in N(v)} h'[s]) + bias.

template<int N>
__global__ __launch_bounds__(256) void k_gemm_mfma(const unsigned short* __restrict__ X,
                                                   const float* __restrict__ W,
                                                   const float* __restrict__ dinv,
                                                   unsigned short* __restrict__ H, int M) {
    constexpr int K = 128;
    constexpr int LDT = K + 8;                 // pad: 2-way-free b128 reads
    __shared__ unsigned short sWt[N * LDT];

    const int tid = threadIdx.x;
    // stage W transposed as bf16 (coalesced f32 reads)
    constexpr int NLOG = (N == 128) ? 7 : 6;
    for (int idx = tid; idx < K * N; idx += 256) {
        int k = idx >> NLOG, c = idx & (N - 1);
        sWt[c * LDT + k] = (unsigned short)f2bf(W[idx]);
    }
    __syncthreads();

    const int wave = __builtin_amdgcn_readfirstlane(tid >> 6);
    const int lane = tid & 63;
    const int m0 = blockIdx.x * 64 + wave * 16;
    if (m0 >= M) return;                        // no syncthreads after this point

    const int arow = lane & 15;
    const int koff = (lane >> 4) * 8;

    // A fragments: 16B each, k0 = 0,32,64,96
    const unsigned short* ap = X + (size_t)(m0 + arow) * K + koff;
    short8 a[4];
    #pragma unroll
    for (int q = 0; q < 4; ++q) a[q] = *(const short8*)(ap + q * 32);

    const int row0 = m0 + (lane >> 4) * 4;
    const float4 dv = *(const float4*)(dinv + row0);   // row0 % 4 == 0, dinv 16B-aligned

    #pragma unroll
    for (int ct = 0; ct < N / 16; ++ct) {
        const int bcol = ct * 16 + (lane & 15);
        const unsigned short* bp = &sWt[bcol * LDT + koff];
        f32x4 acc = {0.f, 0.f, 0.f, 0.f};
        #pragma unroll
        for (int q = 0; q < 4; ++q) {
            short8 b = *(const short8*)(bp + q * 32);
            acc = __builtin_amdgcn_mfma_f32_16x16x32_bf16(a[q], b, acc, 0, 0, 0);
        }
        const int col = ct * 16 + (lane & 15);
        #pragma unroll
        for (int r = 0; r < 4; ++r) {
            float dr = (r == 0) ? dv.x : (r == 1) ? dv.y : (r == 2) ? dv.z : dv.w;
            H[(size_t)(row0 + r) * N + col] = (unsigned short)f2bf(acc[r] * dr);
        }
    }
}

// ================= aggregation over pre-scaled bf16 h': wave owns G=4 nodes, U=16 batches =================
// acc[g] = h'[v] + sum h'[s]  (unweighted!) ; out = dinv[v]*acc + bias (f32 epilogue).
// C=128: lane owns cols (2l,2l+1): one uint gather/lane. C=64: lane owns col l: ushort gather.
// OUTBF: store packed bf16 (feeds next MFMA GEMM); else f32.

template<int C, bool RELU, bool OUTBF>
__global__ __launch_bounds__(256) void k_agg(const void* __restrict__ hraw,
                                             const int* __restrict__ row_ptr,
                                             const int* __restrict__ csr_src,
                                             const float* __restrict__ dinv,
                                             const float* __restrict__ bias,
                                             void* __restrict__ agg, int n) {
    constexpr int G = 4;
    constexpr int U = 16;
    constexpr int VPC = C / 64;          // 2 (C=128) or 1 (C=64)
    const int lane = threadIdx.x & 63;
    const int wv = __builtin_amdgcn_readfirstlane(threadIdx.x >> 6);
    const int v0 = (blockIdx.x * 4 + wv) * G;
    if (v0 >= n) return;

    const unsigned*       hu = (const unsigned*)hraw;        // C=128 view
    const unsigned short* hs = (const unsigned short*)hraw;  // C=64 view

    int rp[G + 1];
    #pragma unroll
    for (int g = 0; g <= G; ++g) rp[g] = row_ptr[min(v0 + g, n)];

    float dd[G];
    float acc[G][VPC];
    #pragma unroll
    for (int g = 0; g < G; ++g) {
        #pragma unroll
        for (int u = 0; u < VPC; ++u) acc[g][u] = 0.f;
        dd[g] = 0.f;
        if (v0 + g < n) {
            dd[g] = dinv[v0 + g];
            if (VPC == 2) {
                unsigned t = hu[(size_t)(v0 + g) * 64 + lane];
                acc[g][0] = bflo(t);
                acc[g][1] = bfhi(t);
            } else {
                acc[g][0] = bflo(hs[(size_t)(v0 + g) * 64 + lane]);
            }
        }
    }

    const int e = rp[G];
    for (int j0 = rp[0]; j0 < e; j0 += U) {
        int ss[U];
        #pragma unroll
        for (int u = 0; u < U; ++u) {
            int s = csr_src[j0 + u];          // contiguous scalar loads
                                              // (<=60B overread into next ws buffer)
            ss[u] = (j0 + u < e) ? s : 0;     // clamp OOB slots
        }
        float hv[U][VPC];
        #pragma unroll
        for (int u = 0; u < U; ++u) {
            if (VPC == 2) {
                unsigned t = hu[(size_t)ss[u] * 64 + lane];
                hv[u][0] = bflo(t);
                hv[u][1] = bfhi(t);
            } else {
                hv[u][0] = bflo(hs[(size_t)ss[u] * 64 + lane]);
            }
        }
        #pragma unroll
        for (int u = 0; u < U; ++u) {
            const int jj = j0 + u;
            #pragma unroll
            for (int g = 0; g < G; ++g) {
                bool in_g = (jj >= rp[g]) && (jj < rp[g + 1]);  // wave-uniform; OOB -> none
                float cg = in_g ? 1.f : 0.f;
                #pragma unroll
                for (int u2 = 0; u2 < VPC; ++u2) acc[g][u2] += cg * hv[u][u2];
            }
        }
    }

    #pragma unroll
    for (int g = 0; g < G; ++g) {
        if (v0 + g < n) {
            if (VPC == 2) {
                float2 bv = ((const float2*)bias)[lane];   // bias[2l], bias[2l+1]
                float ox = acc[g][0] * dd[g] + bv.x;
                float oy = acc[g][1] * dd[g] + bv.y;
                if (RELU) { ox = fmaxf(ox, 0.f); oy = fmaxf(oy, 0.f); }
                if (OUTBF) {
                    ((unsigned*)agg)[(size_t)(v0 + g) * 64 + lane] = (f2bf(oy) << 16) | f2bf(ox);
                } else {
                    ((float2*)agg)[(size_t)(v0 + g) * 64 + lane] = make_float2(ox, oy);
                }
            } else {
                float o = acc[g][0] * dd[g] + bias[lane];
                if (RELU) o = fmaxf(o, 0.f);
                if (OUTBF) ((unsigned short*)agg)[(size_t)(v0 + g) * 64 + lane] = (unsigned short)f2bf(o);
                else       ((float*)agg)[(size_t)(v0 + g) * 64 + lane] = o;
            }
        }
    }
}

// ================= launch =================

extern "C" void kernel_launch(void* const* d_in, const int* in_sizes, int n_in,
                              void* d_out, int out_size, void* d_ws, size_t ws_size,
                              hipStream_t stream) {
    const float* x  = (const float*)d_in[0];
    const int*   ei = (const int*)d_in[1];
    const float* W1 = (const float*)d_in[2];
    const float* b1 = (const float*)d_in[3];
    const float* W2 = (const float*)d_in[4];
    const float* b2 = (const float*)d_in[5];
    float* out = (float*)d_out;

    const int N = in_sizes[0] / C_IN;   // 50000
    const int E = in_sizes[1] / 2;      // 800000

    // 16B-aligned workspace layout
    char* base = (char*)d_ws;
    size_t off = 0;
    auto alloc = [&](size_t bytes) {
        char* q = base + off;
        off = (off + bytes + 15) & ~(size_t)15;
        return q;
    };
    int*   cnt      = (int*)  alloc((size_t)N * 4);
    float* dinv     = (float*)alloc((size_t)N * 4);
    int*   row_ptr  = (int*)  alloc((size_t)(N + 1) * 4);
    int*   pos      = (int*)  alloc((size_t)E * 4);
    int*   bsum     = (int*)  alloc(256 * 4);
    int*   bpre     = (int*)  alloc(256 * 4);
    int*   csr_src  = (int*)  alloc((size_t)E * 4);
    unsigned short* xb   = (unsigned short*)alloc((size_t)N * C_IN * 2);   // bf16 x
    unsigned short* h    = (unsigned short*)alloc((size_t)N * C_HID * 2);  // bf16 h' / h2'
    unsigned short* agg1 = (unsigned short*)alloc((size_t)N * C_HID * 2);  // bf16 agg1
    unsigned short* h2   = h;  // layer-2 h' reuses h (dead after agg128)

    dim3 blk(256);
    const int nbS = (N + 255) / 256;

    k_cvt  <<<((N * C_IN / 4) + 255) / 256, blk, 0, stream>>>((const float4*)x, (uint2*)xb, N * C_IN / 4);

    hipMemsetAsync(cnt, 0, (size_t)N * 4, stream);
    k_count_pos<<<(E + 255) / 256, blk, 0, stream>>>(ei, cnt, pos, E);
    k_dinv <<<nbS, blk, 0, stream>>>(cnt, dinv, N);
    k_scan1<<<nbS, blk, 0, stream>>>(cnt, row_ptr, bsum, N);
    k_scan2<<<1, blk, 0, stream>>>(bsum, bpre, nbS);
    k_scan3<<<nbS, blk, 0, stream>>>(row_ptr, bpre, N, E);
    k_fill2<<<(E + 255) / 256, blk, 0, stream>>>(ei, row_ptr, pos, csr_src, E);

    const int gblocks = (N + 63) / 64;
    const int ablocks = (N + 15) / 16;   // 4 waves x G=4 nodes per block

    // layer 1: h' = dinv * bf16(xb @ W1) ; agg1 = bf16(relu(dinv*(sum h') + b1))
    k_gemm_mfma<C_HID><<<gblocks, blk, 0, stream>>>(xb, W1, dinv, h, N);
    k_agg<C_HID, true, true><<<ablocks, blk, 0, stream>>>(h, row_ptr, csr_src, dinv, b1, agg1, N);

    // layer 2: h2' = dinv * bf16(agg1 @ W2) ; out = dinv*(sum h2') + b2
    k_gemm_mfma<C_OUT><<<gblocks, blk, 0, stream>>>(agg1, W2, dinv, h2, N);
    k_agg<C_OUT, false, false><<<ablocks, blk, 0, stream>>>(h2, row_ptr, csr_src, dinv, b2, out, N);
}

// Round 13
// 169.981 us; speedup vs baseline: 1.3912x; 1.0084x over previous
//
#include <hip/hip_runtime.h>

#define C_IN  128
#define C_HID 128
#define C_OUT 64

typedef __attribute__((ext_vector_type(8))) short short8;
typedef __attribute__((ext_vector_type(4))) float f32x4;

// bf16 helpers (RNE)
__device__ __forceinline__ unsigned f2bf(float f) {
    unsigned u = __float_as_uint(f);
    return (u + 0x7FFF + ((u >> 16) & 1)) >> 16;
}
__device__ __forceinline__ float bflo(unsigned t) { return __uint_as_float(t << 16); }
__device__ __forceinline__ float bfhi(unsigned t) { return __uint_as_float(t & 0xFFFF0000u); }

// ================= x f32 -> bf16 (packed), fused cnt zeroing =================
// Grid (1.6M threads) covers N=50k: thread gid < n also zeroes cnt[gid].
// Replaces hipMemsetAsync(cnt): the runtime's fillBufferAligned took 43us in-graph.

__global__ __launch_bounds__(256) void k_cvt(const float4* __restrict__ in, uint2* __restrict__ outp,
                                             int n4, int* __restrict__ cnt, int n) {
    int i = blockIdx.x * 256 + threadIdx.x;
    if (i < n) cnt[i] = 0;
    if (i < n4) {
        float4 v = in[i];
        uint2 o;
        o.x = (f2bf(v.y) << 16) | f2bf(v.x);
        o.y = (f2bf(v.w) << 16) | f2bf(v.z);
        outp[i] = o;
    }
}

// ================= CSR build =================
// Single atomic pass: count in-degree AND record each edge's slot within its row
// (pos[e] written coalesced by e). Fill pass then needs no atomics.

__global__ __launch_bounds__(256) void k_count_pos(const int* __restrict__ ei, int* __restrict__ cnt,
                                                   int* __restrict__ pos, int E) {
    int e = blockIdx.x * 256 + threadIdx.x;
    if (e < E) pos[e] = atomicAdd(&cnt[ei[E + e]], 1);  // dst
}

__global__ __launch_bounds__(256) void k_dinv(const int* __restrict__ cnt, float* __restrict__ dinv, int n) {
    int i = blockIdx.x * 256 + threadIdx.x;
    if (i < n) dinv[i] = rsqrtf((float)(cnt[i] + 1));  // +1 self-loop
}

__global__ __launch_bounds__(256) void k_scan1(const int* __restrict__ cnt, int* __restrict__ row_ptr,
                                               int* __restrict__ bsum, int n) {
    __shared__ int s[256];
    int tid = threadIdx.x;
    int i = blockIdx.x * 256 + tid;
    int v = (i < n) ? cnt[i] : 0;
    s[tid] = v;
    __syncthreads();
    #pragma unroll
    for (int off = 1; off < 256; off <<= 1) {
        int t = (tid >= off) ? s[tid - off] : 0;
        __syncthreads();
        s[tid] += t;
        __syncthreads();
    }
    if (i < n) row_ptr[i] = s[tid] - v;
    if (tid == 255) bsum[blockIdx.x] = s[255];
}

__global__ __launch_bounds__(256) void k_scan2(const int* __restrict__ bsum, int* __restrict__ bpre, int nb) {
    __shared__ int s[256];
    int tid = threadIdx.x;
    int v = (tid < nb) ? bsum[tid] : 0;
    s[tid] = v;
    __syncthreads();
    #pragma unroll
    for (int off = 1; off < 256; off <<= 1) {
        int t = (tid >= off) ? s[tid - off] : 0;
        __syncthreads();
        s[tid] += t;
        __syncthreads();
    }
    if (tid < nb) bpre[tid] = s[tid] - v;
}

__global__ __launch_bounds__(256) void k_scan3(int* __restrict__ row_ptr,
                                               const int* __restrict__ bpre, int n, int E) {
    int i = blockIdx.x * 256 + threadIdx.x;
    if (i < n) row_ptr[i] += bpre[blockIdx.x];
    if (i == 0) row_ptr[n] = E;
}

// atomic-free fill: slot = row_ptr[d] + pos[e] is unique per edge.
__global__ __launch_bounds__(256) void k_fill2(const int* __restrict__ ei,
                                               const int* __restrict__ row_ptr,
                                               const int* __restrict__ pos,
                                               int* __restrict__ csr_src, int E) {
    int e = blockIdx.x * 256 + threadIdx.x;
    if (e >= E) return;
    int s = ei[e];
    int d = ei[E + e];
    csr_src[row_ptr[d] + pos[e]] = s;
}

// ================= MFMA GEMM: H'bf16[M,N] = dinv[row] * (Xbf16[M,128] @ Wf32[128,N]) =================
// 256 thr = 4 waves; wave w owns 16-row strip (M % 16 == 0). mfma_f32_16x16x32_bf16.
// Output rows pre-scaled by dinv[row] -> aggregation needs NO per-edge coefficients:
//   agg[v] = dinv[v] * (h'[v] + sum_{s in N(v)} h'[s]) + bias.

template<int N>
__global__ __launch_bounds__(256) void k_gemm_mfma(const unsigned short* __restrict__ X,
                                                   const float* __restrict__ W,
                                                   const float* __restrict__ dinv,
                                                   unsigned short* __restrict__ H, int M) {
    constexpr int K = 128;
    constexpr int LDT = K + 8;                 // pad: 2-way-free b128 reads
    __shared__ unsigned short sWt[N * LDT];

    const int tid = threadIdx.x;
    // stage W transposed as bf16 (coalesced f32 reads)
    constexpr int NLOG = (N == 128) ? 7 : 6;
    for (int idx = tid; idx < K * N; idx += 256) {
        int k = idx >> NLOG, c = idx & (N - 1);
        sWt[c * LDT + k] = (unsigned short)f2bf(W[idx]);
    }
    __syncthreads();

    const int wave = __builtin_amdgcn_readfirstlane(tid >> 6);
    const int lane = tid & 63;
    const int m0 = blockIdx.x * 64 + wave * 16;
    if (m0 >= M) return;                        // no syncthreads after this point

    const int arow = lane & 15;
    const int koff = (lane >> 4) * 8;

    // A fragments: 16B each, k0 = 0,32,64,96
    const unsigned short* ap = X + (size_t)(m0 + arow) * K + koff;
    short8 a[4];
    #pragma unroll
    for (int q = 0; q < 4; ++q) a[q] = *(const short8*)(ap + q * 32);

    const int row0 = m0 + (lane >> 4) * 4;
    const float4 dv = *(const float4*)(dinv + row0);   // row0 % 4 == 0, dinv 16B-aligned

    #pragma unroll
    for (int ct = 0; ct < N / 16; ++ct) {
        const int bcol = ct * 16 + (lane & 15);
        const unsigned short* bp = &sWt[bcol * LDT + koff];
        f32x4 acc = {0.f, 0.f, 0.f, 0.f};
        #pragma unroll
        for (int q = 0; q < 4; ++q) {
            short8 b = *(const short8*)(bp + q * 32);
            acc = __builtin_amdgcn_mfma_f32_16x16x32_bf16(a[q], b, acc, 0, 0, 0);
        }
        const int col = ct * 16 + (lane & 15);
        #pragma unroll
        for (int r = 0; r < 4; ++r) {
            float dr = (r == 0) ? dv.x : (r == 1) ? dv.y : (r == 2) ? dv.z : dv.w;
            H[(size_t)(row0 + r) * N + col] = (unsigned short)f2bf(acc[r] * dr);
        }
    }
}

// ================= aggregation over pre-scaled bf16 h': wave owns G=4 nodes, U=16 batches =================
// acc[g] = h'[v] + sum h'[s]  (unweighted!) ; out = dinv[v]*acc + bias (f32 epilogue).
// C=128: lane owns cols (2l,2l+1): one uint gather/lane. C=64: lane owns col l: ushort gather.
// OUTBF: store packed bf16 (feeds next MFMA GEMM); else f32.

template<int C, bool RELU, bool OUTBF>
__global__ __launch_bounds__(256) void k_agg(const void* __restrict__ hraw,
                                             const int* __restrict__ row_ptr,
                                             const int* __restrict__ csr_src,
                                             const float* __restrict__ dinv,
                                             const float* __restrict__ bias,
                                             void* __restrict__ agg, int n) {
    constexpr int G = 4;
    constexpr int U = 16;
    constexpr int VPC = C / 64;          // 2 (C=128) or 1 (C=64)
    const int lane = threadIdx.x & 63;
    const int wv = __builtin_amdgcn_readfirstlane(threadIdx.x >> 6);
    const int v0 = (blockIdx.x * 4 + wv) * G;
    if (v0 >= n) return;

    const unsigned*       hu = (const unsigned*)hraw;        // C=128 view
    const unsigned short* hs = (const unsigned short*)hraw;  // C=64 view

    int rp[G + 1];
    #pragma unroll
    for (int g = 0; g <= G; ++g) rp[g] = row_ptr[min(v0 + g, n)];

    float dd[G];
    float acc[G][VPC];
    #pragma unroll
    for (int g = 0; g < G; ++g) {
        #pragma unroll
        for (int u = 0; u < VPC; ++u) acc[g][u] = 0.f;
        dd[g] = 0.f;
        if (v0 + g < n) {
            dd[g] = dinv[v0 + g];
            if (VPC == 2) {
                unsigned t = hu[(size_t)(v0 + g) * 64 + lane];
                acc[g][0] = bflo(t);
                acc[g][1] = bfhi(t);
            } else {
                acc[g][0] = bflo(hs[(size_t)(v0 + g) * 64 + lane]);
            }
        }
    }

    const int e = rp[G];
    for (int j0 = rp[0]; j0 < e; j0 += U) {
        int ss[U];
        #pragma unroll
        for (int u = 0; u < U; ++u) {
            int s = csr_src[j0 + u];          // contiguous scalar loads
                                              // (<=60B overread into next ws buffer)
            ss[u] = (j0 + u < e) ? s : 0;     // clamp OOB slots
        }
        float hv[U][VPC];
        #pragma unroll
        for (int u = 0; u < U; ++u) {
            if (VPC == 2) {
                unsigned t = hu[(size_t)ss[u] * 64 + lane];
                hv[u][0] = bflo(t);
                hv[u][1] = bfhi(t);
            } else {
                hv[u][0] = bflo(hs[(size_t)ss[u] * 64 + lane]);
            }
        }
        #pragma unroll
        for (int u = 0; u < U; ++u) {
            const int jj = j0 + u;
            #pragma unroll
            for (int g = 0; g < G; ++g) {
                bool in_g = (jj >= rp[g]) && (jj < rp[g + 1]);  // wave-uniform; OOB -> none
                float cg = in_g ? 1.f : 0.f;
                #pragma unroll
                for (int u2 = 0; u2 < VPC; ++u2) acc[g][u2] += cg * hv[u][u2];
            }
        }
    }

    #pragma unroll
    for (int g = 0; g < G; ++g) {
        if (v0 + g < n) {
            if (VPC == 2) {
                float2 bv = ((const float2*)bias)[lane];   // bias[2l], bias[2l+1]
                float ox = acc[g][0] * dd[g] + bv.x;
                float oy = acc[g][1] * dd[g] + bv.y;
                if (RELU) { ox = fmaxf(ox, 0.f); oy = fmaxf(oy, 0.f); }
                if (OUTBF) {
                    ((unsigned*)agg)[(size_t)(v0 + g) * 64 + lane] = (f2bf(oy) << 16) | f2bf(ox);
                } else {
                    ((float2*)agg)[(size_t)(v0 + g) * 64 + lane] = make_float2(ox, oy);
                }
            } else {
                float o = acc[g][0] * dd[g] + bias[lane];
                if (RELU) o = fmaxf(o, 0.f);
                if (OUTBF) ((unsigned short*)agg)[(size_t)(v0 + g) * 64 + lane] = (unsigned short)f2bf(o);
                else       ((float*)agg)[(size_t)(v0 + g) * 64 + lane] = o;
            }
        }
    }
}

// ================= launch =================

extern "C" void kernel_launch(void* const* d_in, const int* in_sizes, int n_in,
                              void* d_out, int out_size, void* d_ws, size_t ws_size,
                              hipStream_t stream) {
    const float* x  = (const float*)d_in[0];
    const int*   ei = (const int*)d_in[1];
    const float* W1 = (const float*)d_in[2];
    const float* b1 = (const float*)d_in[3];
    const float* W2 = (const float*)d_in[4];
    const float* b2 = (const float*)d_in[5];
    float* out = (float*)d_out;

    const int N = in_sizes[0] / C_IN;   // 50000
    const int E = in_sizes[1] / 2;      // 800000

    // 16B-aligned workspace layout
    char* base = (char*)d_ws;
    size_t off = 0;
    auto alloc = [&](size_t bytes) {
        char* q = base + off;
        off = (off + bytes + 15) & ~(size_t)15;
        return q;
    };
    int*   cnt      = (int*)  alloc((size_t)N * 4);
    float* dinv     = (float*)alloc((size_t)N * 4);
    int*   row_ptr  = (int*)  alloc((size_t)(N + 1) * 4);
    int*   pos      = (int*)  alloc((size_t)E * 4);
    int*   bsum     = (int*)  alloc(256 * 4);
    int*   bpre     = (int*)  alloc(256 * 4);
    int*   csr_src  = (int*)  alloc((size_t)E * 4);
    unsigned short* xb   = (unsigned short*)alloc((size_t)N * C_IN * 2);   // bf16 x
    unsigned short* h    = (unsigned short*)alloc((size_t)N * C_HID * 2);  // bf16 h' / h2'
    unsigned short* agg1 = (unsigned short*)alloc((size_t)N * C_HID * 2);  // bf16 agg1
    unsigned short* h2   = h;  // layer-2 h' reuses h (dead after agg128)

    dim3 blk(256);
    const int nbS = (N + 255) / 256;

    // fused: bf16 conversion of x + cnt zeroing (replaces slow hipMemsetAsync)
    k_cvt<<<((N * C_IN / 4) + 255) / 256, blk, 0, stream>>>((const float4*)x, (uint2*)xb,
                                                            N * C_IN / 4, cnt, N);

    k_count_pos<<<(E + 255) / 256, blk, 0, stream>>>(ei, cnt, pos, E);
    k_dinv <<<nbS, blk, 0, stream>>>(cnt, dinv, N);
    k_scan1<<<nbS, blk, 0, stream>>>(cnt, row_ptr, bsum, N);
    k_scan2<<<1, blk, 0, stream>>>(bsum, bpre, nbS);
    k_scan3<<<nbS, blk, 0, stream>>>(row_ptr, bpre, N, E);
    k_fill2<<<(E + 255) / 256, blk, 0, stream>>>(ei, row_ptr, pos, csr_src, E);

    const int gblocks = (N + 63) / 64;
    const int ablocks = (N + 15) / 16;   // 4 waves x G=4 nodes per block

    // layer 1: h' = dinv * bf16(xb @ W1) ; agg1 = bf16(relu(dinv*(sum h') + b1))
    k_gemm_mfma<C_HID><<<gblocks, blk, 0, stream>>>(xb, W1, dinv, h, N);
    k_agg<C_HID, true, true><<<ablocks, blk, 0, stream>>>(h, row_ptr, csr_src, dinv, b1, agg1, N);

    // layer 2: h2' = dinv * bf16(agg1 @ W2) ; out = dinv*(sum h2') + b2
    k_gemm_mfma<C_OUT><<<gblocks, blk, 0, stream>>>(agg1, W2, dinv, h2, N);
    k_agg<C_OUT, false, false><<<ablocks, blk, 0, stream>>>(h2, row_ptr, csr_src, dinv, b2, out, N);
}